// Round 5
// baseline (86.011 us; speedup 1.0000x reference)
//
#include <hip/hip_runtime.h>
#include <hip/hip_bf16.h>

// Problem constants (match reference)
#define T_TOK 8192
#define DDIM  1024
#define HDIM  512
#define NE    8
#define TPE   (T_TOK / NE)   // 1024 tokens per expert (static partition per reference)

typedef __attribute__((ext_vector_type(4))) float floatx4;
typedef __attribute__((ext_vector_type(8))) short bf16x8;

// packed f32x2 -> bf16x2 (RNE), single instruction
__device__ __forceinline__ unsigned int cvt_pk_bf16(float lo, float hi) {
    unsigned int r;
    asm("v_cvt_pk_bf16_f32 %0, %1, %2" : "=v"(r) : "v"(lo), "v"(hi));
    return r;
}

// XCD-aware swizzle for 512-block grids (512 % 8 == 0 -> bijective):
// each XCD gets a contiguous chunk of 64 logical blocks (= one expert).
__device__ __forceinline__ int xcd_swizzle_512(int raw) {
    return (raw & 7) * 64 + (raw >> 3);
}

// ---------------------------------------------------------------------------
// Kernel 1: h = silu(X W1^T) * (X W3^T), dequant + fp32->bf16 fused into
// reg-staged LDS staging (global->reg->convert->ds_write).
// Tile: M=128 tokens x 64 h-cols (paired w1+w3 => 128 B rows), BK=64, K=1024.
// Double-buffered LDS, prefetch-next-tile-into-regs, ONE barrier per K-step:
//   WRITE(b) ; LOAD(t+1) ; lgkmcnt(0) ; s_barrier ; COMPUTE(b)
// (write always targets the buffer no concurrent wave is reading: program
//  order WRITE(b)->bar->COMPUTE(b) makes the post-compute barrier redundant.)
// 4 waves 2x2; grid = 512, LDS 64 KB -> 2 blocks/CU.
// ---------------------------------------------------------------------------
__global__ __launch_bounds__(256, 2)
void gemm1_silu_kernel(const float* __restrict__ X,
                       const float* __restrict__ S,
                       const float* __restrict__ W13,
                       __hip_bfloat16* __restrict__ Hout)
{
    const int bid = xcd_swizzle_512(blockIdx.x);
    const int e  = bid >> 6;
    const int mt = (bid >> 3) & 7;    // token tile (128 rows)
    const int nt = bid & 7;           // h tile (64 cols)
    const int tok0 = e * TPE + mt * 128;
    const float* __restrict__ We = W13 + (size_t)e * (2 * HDIM) * DDIM;

    __shared__ __hip_bfloat16 sA[2][128][64];
    __shared__ __hip_bfloat16 sB[2][128][64];

    const int tid  = threadIdx.x;
    const int lane = tid & 63;
    const int wave = tid >> 6;
    const int wr = wave >> 1;   // 0..1 (M half)
    const int wc = wave & 1;    // 0..1 (N: 32 cols each)
    const int lr = lane & 15;
    const int lk = (lane >> 4) * 8;

    floatx4 acc1[4][2] = {};
    floatx4 acc3[4][2] = {};

    // staging geometry: chunk = (row, 8-el col span); thread owns 4 A-chunks
    // and 4 B-chunks per K-step.
    const int srow0 = (tid >> 3);     // 0..31
    const int scol  = (tid & 7) * 8;  // 0..56

    float4 rA[8]; float rs[4]; float4 rB[8];

    auto LOAD = [&](int kk) {
        const int k0 = kk * 64;
        #pragma unroll
        for (int j = 0; j < 4; ++j) {
            int row = srow0 + j * 32;
            const float* pa = &X[(size_t)(tok0 + row) * DDIM + k0 + scol];
            rA[2*j]   = *reinterpret_cast<const float4*>(pa);
            rA[2*j+1] = *reinterpret_cast<const float4*>(pa + 4);
            rs[j] = S[(size_t)(tok0 + row) * (DDIM / 32) + ((k0 + scol) >> 5)];
            int wrow = (j < 2) ? (nt * 64 + row)                 // w1 rows
                               : (HDIM + nt * 64 + (row - 64));  // w3 rows
            const float* pb = &We[(size_t)wrow * DDIM + k0 + scol];
            rB[2*j]   = *reinterpret_cast<const float4*>(pb);
            rB[2*j+1] = *reinterpret_cast<const float4*>(pb + 4);
        }
    };
    auto WRITE = [&](int buf) {
        #pragma unroll
        for (int j = 0; j < 4; ++j) {
            int row = srow0 + j * 32;
            float sc = rs[j];
            uint4 pa;
            pa.x = cvt_pk_bf16(rA[2*j].x * sc,   rA[2*j].y * sc);
            pa.y = cvt_pk_bf16(rA[2*j].z * sc,   rA[2*j].w * sc);
            pa.z = cvt_pk_bf16(rA[2*j+1].x * sc, rA[2*j+1].y * sc);
            pa.w = cvt_pk_bf16(rA[2*j+1].z * sc, rA[2*j+1].w * sc);
            *reinterpret_cast<uint4*>(&sA[buf][row][scol]) = pa;
            uint4 pb;
            pb.x = cvt_pk_bf16(rB[2*j].x,   rB[2*j].y);
            pb.y = cvt_pk_bf16(rB[2*j].z,   rB[2*j].w);
            pb.z = cvt_pk_bf16(rB[2*j+1].x, rB[2*j+1].y);
            pb.w = cvt_pk_bf16(rB[2*j+1].z, rB[2*j+1].w);
            *reinterpret_cast<uint4*>(&sB[buf][row][scol]) = pb;
        }
    };
    auto COMPUTE = [&](int buf) {
        #pragma unroll
        for (int ks = 0; ks < 2; ++ks) {
            bf16x8 a[4], b1[2], b3[2];
            #pragma unroll
            for (int m = 0; m < 4; ++m)
                a[m] = *reinterpret_cast<const bf16x8*>(&sA[buf][wr * 64 + m * 16 + lr][ks * 32 + lk]);
            #pragma unroll
            for (int n = 0; n < 2; ++n) {
                b1[n] = *reinterpret_cast<const bf16x8*>(&sB[buf][wc * 32 + n * 16 + lr][ks * 32 + lk]);
                b3[n] = *reinterpret_cast<const bf16x8*>(&sB[buf][64 + wc * 32 + n * 16 + lr][ks * 32 + lk]);
            }
            #pragma unroll
            for (int m = 0; m < 4; ++m)
                #pragma unroll
                for (int n = 0; n < 2; ++n) {
                    acc1[m][n] = __builtin_amdgcn_mfma_f32_16x16x32_bf16(a[m], b1[n], acc1[m][n], 0, 0, 0);
                    acc3[m][n] = __builtin_amdgcn_mfma_f32_16x16x32_bf16(a[m], b3[n], acc3[m][n], 0, 0, 0);
                }
        }
    };

    LOAD(0);
    for (int kk = 0; kk < DDIM / 64; ++kk) {       // 16 K-steps
        const int buf = kk & 1;
        WRITE(buf);
        if (kk < DDIM / 64 - 1) LOAD(kk + 1);      // next tile flies under compute
        asm volatile("s_waitcnt lgkmcnt(0)" ::: "memory");
        __builtin_amdgcn_sched_barrier(0);
        __builtin_amdgcn_s_barrier();
        COMPUTE(buf);
    }

    // ---- epilogue: h = silu(h1) * h3 -> bf16
    const int hcol0 = nt * 64 + wc * 32;
    #pragma unroll
    for (int m = 0; m < 4; ++m) {
        #pragma unroll
        for (int n = 0; n < 2; ++n) {
            #pragma unroll
            for (int i = 0; i < 4; ++i) {
                int row = tok0 + wr * 64 + m * 16 + (lane >> 4) * 4 + i;
                int col = hcol0 + n * 16 + (lane & 15);
                float h1 = acc1[m][n][i];
                float h3 = acc3[m][n][i];
                float sig = 1.0f / (1.0f + __expf(-h1));
                Hout[(size_t)row * HDIM + col] = __float2bfloat16(h1 * sig * h3);
            }
        }
    }
}

// ---------------------------------------------------------------------------
// Kernel 2: out = h W2^T. A = h (bf16, reg-copied), B = W2 (fp32 -> bf16
// converted in staging). Same 1-barrier reg-staged dbuf structure.
// Tile 128x128, BK=64, K=512 (8 K-steps). grid = 512, LDS 64 KB.
// ---------------------------------------------------------------------------
__global__ __launch_bounds__(256, 2)
void gemm2_kernel(const __hip_bfloat16* __restrict__ Hin,
                  const float* __restrict__ W2,
                  float* __restrict__ Out)
{
    const int bid = xcd_swizzle_512(blockIdx.x);
    const int e  = bid >> 6;
    const int mt = (bid >> 3) & 7;
    const int nt = bid & 7;
    const int tok0 = e * TPE + mt * 128;
    const float* __restrict__ We = W2 + (size_t)e * DDIM * HDIM;

    __shared__ __hip_bfloat16 sA[2][128][64];
    __shared__ __hip_bfloat16 sB[2][128][64];

    const int tid  = threadIdx.x;
    const int lane = tid & 63;
    const int wave = tid >> 6;
    const int wr = wave >> 1;
    const int wc = wave & 1;
    const int lr = lane & 15;
    const int lk = (lane >> 4) * 8;

    floatx4 acc[4][4] = {};

    const int srow0 = (tid >> 3);
    const int scol  = (tid & 7) * 8;

    uint4 ra[4]; float4 rB[8];

    auto LOAD = [&](int kk) {
        const int k0 = kk * 64;
        #pragma unroll
        for (int j = 0; j < 4; ++j) {
            int row = srow0 + j * 32;
            ra[j] = *reinterpret_cast<const uint4*>(
                &Hin[(size_t)(tok0 + row) * HDIM + k0 + scol]);
            const float* pb = &We[(size_t)(nt * 128 + row) * HDIM + k0 + scol];
            rB[2*j]   = *reinterpret_cast<const float4*>(pb);
            rB[2*j+1] = *reinterpret_cast<const float4*>(pb + 4);
        }
    };
    auto WRITE = [&](int buf) {
        #pragma unroll
        for (int j = 0; j < 4; ++j) {
            int row = srow0 + j * 32;
            *reinterpret_cast<uint4*>(&sA[buf][row][scol]) = ra[j];
            uint4 pb;
            pb.x = cvt_pk_bf16(rB[2*j].x,   rB[2*j].y);
            pb.y = cvt_pk_bf16(rB[2*j].z,   rB[2*j].w);
            pb.z = cvt_pk_bf16(rB[2*j+1].x, rB[2*j+1].y);
            pb.w = cvt_pk_bf16(rB[2*j+1].z, rB[2*j+1].w);
            *reinterpret_cast<uint4*>(&sB[buf][row][scol]) = pb;
        }
    };
    auto COMPUTE = [&](int buf) {
        #pragma unroll
        for (int ks = 0; ks < 2; ++ks) {
            bf16x8 a[4], b[4];
            #pragma unroll
            for (int m = 0; m < 4; ++m)
                a[m] = *reinterpret_cast<const bf16x8*>(&sA[buf][wr * 64 + m * 16 + lr][ks * 32 + lk]);
            #pragma unroll
            for (int n = 0; n < 4; ++n)
                b[n] = *reinterpret_cast<const bf16x8*>(&sB[buf][wc * 64 + n * 16 + lr][ks * 32 + lk]);
            #pragma unroll
            for (int m = 0; m < 4; ++m)
                #pragma unroll
                for (int n = 0; n < 4; ++n)
                    acc[m][n] = __builtin_amdgcn_mfma_f32_16x16x32_bf16(a[m], b[n], acc[m][n], 0, 0, 0);
        }
    };

    LOAD(0);
    for (int kk = 0; kk < HDIM / 64; ++kk) {       // 8 K-steps
        const int buf = kk & 1;
        WRITE(buf);
        if (kk < HDIM / 64 - 1) LOAD(kk + 1);
        asm volatile("s_waitcnt lgkmcnt(0)" ::: "memory");
        __builtin_amdgcn_sched_barrier(0);
        __builtin_amdgcn_s_barrier();
        COMPUTE(buf);
    }

    const int dcol0 = nt * 128 + wc * 64;
    #pragma unroll
    for (int m = 0; m < 4; ++m) {
        #pragma unroll
        for (int n = 0; n < 4; ++n) {
            #pragma unroll
            for (int i = 0; i < 4; ++i) {
                int row = tok0 + wr * 64 + m * 16 + (lane >> 4) * 4 + i;
                int col = dcol0 + n * 16 + (lane & 15);
                Out[(size_t)row * DDIM + col] = acc[m][n][i];
            }
        }
    }
}

extern "C" void kernel_launch(void* const* d_in, const int* in_sizes, int n_in,
                              void* d_out, int out_size, void* d_ws, size_t ws_size,
                              hipStream_t stream) {
    const float* X   = (const float*)d_in[0];   // (T, D) fp32
    const float* S   = (const float*)d_in[1];   // (T, D/32) fp32
    const float* W13 = (const float*)d_in[4];   // (E, 2H, D) fp32
    const float* W2  = (const float*)d_in[5];   // (E, D, H) fp32
    float* Out = (float*)d_out;                 // (T, D) fp32

    // workspace: Hb bf16 (T*H) = 8 MiB
    __hip_bfloat16* Hb = (__hip_bfloat16*)d_ws;

    gemm1_silu_kernel<<<NE * 8 * 8, 256, 0, stream>>>(X, S, W13, Hb);
    gemm2_kernel<<<NE * 8 * 8, 256, 0, stream>>>(Hb, W2, Out);
}

// Round 6
// 58.646 us; speedup vs baseline: 1.4666x; 1.4666x over previous
//
#include <hip/hip_runtime.h>
#include <hip/hip_bf16.h>

// Problem constants (match reference)
#define T_TOK 8192
#define DDIM  1024
#define HDIM  512
#define NE    8
#define TPE   (T_TOK / NE)   // 1024 tokens per expert (static partition per reference)

typedef __attribute__((ext_vector_type(4))) float floatx4;
typedef __attribute__((ext_vector_type(8))) short bf16x8;

__device__ __forceinline__ unsigned short f2bf(float f) {
    union { float f; unsigned int u; } v;
    v.f = f;
    unsigned int u = v.u;
    unsigned int r = u + 0x7FFFu + ((u >> 16) & 1u);  // RNE
    return (unsigned short)(r >> 16);
}

// async global -> LDS, 16 bytes per lane (dest must be linear: base + lane*16)
__device__ __forceinline__ void gld_lds16(const void* g, void* l) {
    __builtin_amdgcn_global_load_lds(
        (const __attribute__((address_space(1))) unsigned int*)g,
        (__attribute__((address_space(3))) unsigned int*)l, 16, 0, 0);
}

// ---------------------------------------------------------------------------
// Kernel 0 (streaming): W13 fp32->bf16, W2 fp32->bf16, X*scale -> bf16.
// ---------------------------------------------------------------------------
__global__ __launch_bounds__(256)
void convert_kernel(const float* __restrict__ X, const float* __restrict__ S,
                    const float* __restrict__ W13, const float* __restrict__ W2,
                    unsigned short* __restrict__ Xb,
                    unsigned short* __restrict__ W13b,
                    unsigned short* __restrict__ W2b)
{
    const int NTX  = (T_TOK * DDIM) / 4;           // 2,097,152 float4 chunks
    const int NT13 = (NE * 2 * HDIM * DDIM) / 4;   // 2,097,152
    const int NT2  = (NE * DDIM * HDIM) / 4;       // 1,048,576
    const int stride = gridDim.x * blockDim.x;
    for (int i = blockIdx.x * blockDim.x + threadIdx.x; i < NTX + NT13 + NT2; i += stride) {
        float4 v;
        ushort4* dst;
        if (i < NTX) {
            int row = i >> 8;            // D/4 = 256 chunks per row
            int c4  = i & 255;
            v = reinterpret_cast<const float4*>(X)[i];
            float sc = S[row * (DDIM / 32) + (c4 >> 3)];
            v.x *= sc; v.y *= sc; v.z *= sc; v.w *= sc;
            dst = (ushort4*)Xb + i;
        } else if (i < NTX + NT13) {
            int j = i - NTX;
            v = reinterpret_cast<const float4*>(W13)[j];
            dst = (ushort4*)W13b + j;
        } else {
            int j = i - NTX - NT13;
            v = reinterpret_cast<const float4*>(W2)[j];
            dst = (ushort4*)W2b + j;
        }
        ushort4 b;
        b.x = f2bf(v.x); b.y = f2bf(v.y); b.z = f2bf(v.z); b.w = f2bf(v.w);
        *dst = b;
    }
}

// XCD-aware swizzle for 512-block grids (512 % 8 == 0 -> bijective):
// each XCD gets a contiguous chunk of 64 logical blocks (= one expert).
__device__ __forceinline__ int xcd_swizzle_512(int raw) {
    return (raw & 7) * 64 + (raw >> 3);
}

// LDS tile layout: [128 rows][8 slots of 16B]. Bank-conflict swizzle (T2/G21):
//   LDS dest stays LINEAR (global_load_lds requirement);
//   global SOURCE slot is pre-permuted: src_slot = dst_slot ^ (row & 7);
//   ds_read column applies the same XOR: phys_slot = log_slot ^ (row & 7).
// Read pattern (16 rows x same slot) then spreads over 8 slots -> 2-way (free).

// ---------------------------------------------------------------------------
// Kernel 1: h = silu(Xb W1^T) * (Xb W3^T). Pure bf16, gld_lds both operands.
// Tile: M=128 tokens x 64 h-cols (paired w1+w3 => 128 B rows), BK=64, K=1024.
// Double-buffered LDS + prefetch-next-tile + counted vmcnt(8).
// 4 waves 2x2; grid = 512, LDS 64 KB -> 2 blocks/CU.
// ---------------------------------------------------------------------------
__global__ __launch_bounds__(256, 2)
void gemm1_silu_kernel(const unsigned short* __restrict__ Xb,
                       const unsigned short* __restrict__ W13b,
                       __hip_bfloat16* __restrict__ Hout)
{
    const int bid = xcd_swizzle_512(blockIdx.x);
    const int e  = bid >> 6;
    const int mt = (bid >> 3) & 7;    // token tile (128 rows)
    const int nt = bid & 7;           // h tile (64 cols)
    const int tok0 = e * TPE + mt * 128;
    const unsigned short* __restrict__ We = W13b + (size_t)e * (2 * HDIM) * DDIM;

    __shared__ __hip_bfloat16 sA[2][128][64];
    __shared__ __hip_bfloat16 sB[2][128][64];

    const int tid  = threadIdx.x;
    const int lane = tid & 63;
    const int wave = tid >> 6;
    const int wr = wave >> 1;   // 0..1 (M half)
    const int wc = wave & 1;    // 0..1 (N: 32 cols each)
    const int lr = lane & 15;
    // swizzled read column base: phys_slot(ks) = (sw0 ^ (ks<<2)) ; col = slot*8
    const int sw0 = ((lane >> 4) ^ (lane & 7));

    floatx4 acc1[4][2] = {};
    floatx4 acc3[4][2] = {};

    // staging geometry: LDS dest linear (row = tid>>3, slot = tid&7);
    // global source slot pre-swizzled by row&7.
    const int srow0 = (tid >> 3);                               // 0..31
    const int dcol  = (tid & 7) * 8;                            // LDS dest col
    const int gcol  = ((tid & 7) ^ (srow0 & 7)) * 8;            // global src col

    auto STAGE = [&](int kk, int buf) {
        const int k0 = kk * 64;
        #pragma unroll
        for (int j = 0; j < 4; ++j) {
            int row = srow0 + j * 32;   // j*32 keeps row&7 constant
            gld_lds16(&Xb[(size_t)(tok0 + row) * DDIM + k0 + gcol],
                      &sA[buf][row][dcol]);
            int wrow = (j < 2) ? (nt * 64 + row)                    // w1 rows
                               : (HDIM + nt * 64 + (row - 64));     // w3 rows
            gld_lds16(&We[(size_t)wrow * DDIM + k0 + gcol],
                      &sB[buf][row][dcol]);
        }
    };
    auto COMPUTE = [&](int buf) {
        #pragma unroll
        for (int ks = 0; ks < 2; ++ks) {
            const int rc = (sw0 ^ (ks << 2)) << 3;   // swizzled read col (elems)
            bf16x8 a[4], b1[2], b3[2];
            #pragma unroll
            for (int m = 0; m < 4; ++m)
                a[m] = *reinterpret_cast<const bf16x8*>(&sA[buf][wr * 64 + m * 16 + lr][rc]);
            #pragma unroll
            for (int n = 0; n < 2; ++n) {
                b1[n] = *reinterpret_cast<const bf16x8*>(&sB[buf][wc * 32 + n * 16 + lr][rc]);
                b3[n] = *reinterpret_cast<const bf16x8*>(&sB[buf][64 + wc * 32 + n * 16 + lr][rc]);
            }
            #pragma unroll
            for (int m = 0; m < 4; ++m)
                #pragma unroll
                for (int n = 0; n < 2; ++n) {
                    acc1[m][n] = __builtin_amdgcn_mfma_f32_16x16x32_bf16(a[m], b1[n], acc1[m][n], 0, 0, 0);
                    acc3[m][n] = __builtin_amdgcn_mfma_f32_16x16x32_bf16(a[m], b3[n], acc3[m][n], 0, 0, 0);
                }
        }
    };

    STAGE(0, 0);
    for (int kk = 0; kk < DDIM / 64 - 1; ++kk) {       // kk = 0..14
        STAGE(kk + 1, (kk + 1) & 1);
        asm volatile("s_waitcnt vmcnt(8)" ::: "memory");  // current tile landed
        __builtin_amdgcn_sched_barrier(0);
        __builtin_amdgcn_s_barrier();
        COMPUTE(kk & 1);
        __builtin_amdgcn_s_barrier();                  // guard buf before next STAGE
    }
    asm volatile("s_waitcnt vmcnt(0)" ::: "memory");
    __builtin_amdgcn_sched_barrier(0);
    __builtin_amdgcn_s_barrier();
    COMPUTE(1);                                        // tile 15

    // ---- epilogue: h = silu(h1) * h3 -> bf16
    const int hcol0 = nt * 64 + wc * 32;
    #pragma unroll
    for (int m = 0; m < 4; ++m) {
        #pragma unroll
        for (int n = 0; n < 2; ++n) {
            #pragma unroll
            for (int i = 0; i < 4; ++i) {
                int row = tok0 + wr * 64 + m * 16 + (lane >> 4) * 4 + i;
                int col = hcol0 + n * 16 + (lane & 15);
                float h1 = acc1[m][n][i];
                float h3 = acc3[m][n][i];
                float sig = 1.0f / (1.0f + __expf(-h1));
                Hout[(size_t)row * HDIM + col] = __float2bfloat16(h1 * sig * h3);
            }
        }
    }
}

// ---------------------------------------------------------------------------
// Kernel 2: out = h W2^T. All-bf16, gld_lds, same prefetch + swizzle.
// Tile 128x128, BK=64, K=512 (8 K-steps). grid = 512, LDS 64 KB.
// ---------------------------------------------------------------------------
__global__ __launch_bounds__(256, 2)
void gemm2_kernel(const __hip_bfloat16* __restrict__ Hin,
                  const unsigned short* __restrict__ W2b,
                  float* __restrict__ Out)
{
    const int bid = xcd_swizzle_512(blockIdx.x);
    const int e  = bid >> 6;
    const int mt = (bid >> 3) & 7;
    const int nt = bid & 7;
    const int tok0 = e * TPE + mt * 128;
    const unsigned short* __restrict__ We = W2b + (size_t)e * DDIM * HDIM;

    __shared__ __hip_bfloat16 sA[2][128][64];
    __shared__ __hip_bfloat16 sB[2][128][64];

    const int tid  = threadIdx.x;
    const int lane = tid & 63;
    const int wave = tid >> 6;
    const int wr = wave >> 1;
    const int wc = wave & 1;
    const int lr = lane & 15;
    const int sw0 = ((lane >> 4) ^ (lane & 7));

    floatx4 acc[4][4] = {};

    const int srow0 = (tid >> 3);
    const int dcol  = (tid & 7) * 8;
    const int gcol  = ((tid & 7) ^ (srow0 & 7)) * 8;

    auto STAGE = [&](int kk, int buf) {
        const int k0 = kk * 64;
        #pragma unroll
        for (int j = 0; j < 4; ++j) {
            int row = srow0 + j * 32;
            gld_lds16(&Hin[(size_t)(tok0 + row) * HDIM + k0 + gcol],
                      &sA[buf][row][dcol]);
            gld_lds16(&We[(size_t)(nt * 128 + row) * HDIM + k0 + gcol],
                      &sB[buf][row][dcol]);
        }
    };
    auto COMPUTE = [&](int buf) {
        #pragma unroll
        for (int ks = 0; ks < 2; ++ks) {
            const int rc = (sw0 ^ (ks << 2)) << 3;
            bf16x8 a[4], b[4];
            #pragma unroll
            for (int m = 0; m < 4; ++m)
                a[m] = *reinterpret_cast<const bf16x8*>(&sA[buf][wr * 64 + m * 16 + lr][rc]);
            #pragma unroll
            for (int n = 0; n < 4; ++n)
                b[n] = *reinterpret_cast<const bf16x8*>(&sB[buf][wc * 64 + n * 16 + lr][rc]);
            #pragma unroll
            for (int m = 0; m < 4; ++m)
                #pragma unroll
                for (int n = 0; n < 4; ++n)
                    acc[m][n] = __builtin_amdgcn_mfma_f32_16x16x32_bf16(a[m], b[n], acc[m][n], 0, 0, 0);
        }
    };

    STAGE(0, 0);
    for (int kk = 0; kk < HDIM / 64 - 1; ++kk) {       // kk = 0..6
        STAGE(kk + 1, (kk + 1) & 1);
        asm volatile("s_waitcnt vmcnt(8)" ::: "memory");
        __builtin_amdgcn_sched_barrier(0);
        __builtin_amdgcn_s_barrier();
        COMPUTE(kk & 1);
        __builtin_amdgcn_s_barrier();
    }
    asm volatile("s_waitcnt vmcnt(0)" ::: "memory");
    __builtin_amdgcn_sched_barrier(0);
    __builtin_amdgcn_s_barrier();
    COMPUTE(1);                                        // tile 7

    const int dcol0 = nt * 128 + wc * 64;
    #pragma unroll
    for (int m = 0; m < 4; ++m) {
        #pragma unroll
        for (int n = 0; n < 4; ++n) {
            #pragma unroll
            for (int i = 0; i < 4; ++i) {
                int row = tok0 + wr * 64 + m * 16 + (lane >> 4) * 4 + i;
                int col = dcol0 + n * 16 + (lane & 15);
                Out[(size_t)row * DDIM + col] = acc[m][n][i];
            }
        }
    }
}

extern "C" void kernel_launch(void* const* d_in, const int* in_sizes, int n_in,
                              void* d_out, int out_size, void* d_ws, size_t ws_size,
                              hipStream_t stream) {
    const float* X   = (const float*)d_in[0];   // (T, D) fp32
    const float* S   = (const float*)d_in[1];   // (T, D/32) fp32
    const float* W13 = (const float*)d_in[4];   // (E, 2H, D) fp32
    const float* W2  = (const float*)d_in[5];   // (E, D, H) fp32
    float* Out = (float*)d_out;                 // (T, D) fp32

    // workspace layout (bytes):
    //   [0, 16Mi)    W13b bf16 (E*2H*D)
    //   [16Mi, 24Mi) W2b  bf16 (E*D*H)
    //   [24Mi, 32Mi) Hb   bf16 (T*H)
    // Xb (T*D bf16 = 16 MiB) lives in d_out's first half: gemm1 consumes it,
    // then gemm2 overwrites all of d_out with the final fp32 output.
    unsigned short* W13b = (unsigned short*)d_ws;
    unsigned short* W2b  = W13b + (size_t)NE * 2 * HDIM * DDIM;
    __hip_bfloat16* Hb   = (__hip_bfloat16*)(W2b + (size_t)NE * DDIM * HDIM);
    unsigned short* Xb   = (unsigned short*)d_out;

    convert_kernel<<<2048, 256, 0, stream>>>(X, S, W13, W2, Xb, W13b, W2b);
    gemm1_silu_kernel<<<NE * 8 * 8, 256, 0, stream>>>(Xb, W13b, Hb);
    gemm2_kernel<<<NE * 8 * 8, 256, 0, stream>>>(Hb, W2b, Out);
}